// Round 1
// baseline (204.792 us; speedup 1.0000x reference)
//
#include <hip/hip_runtime.h>
#include <math.h>

typedef __attribute__((ext_vector_type(4))) float f32x4;
typedef __attribute__((ext_vector_type(4))) _Float16 f16x4;

#define B_  16
#define D_  2048
#define H_  16
#define HD_ 128
#define LP_ 2048
#define M_  8192
#define QKV_R (3 * D_)
#define SCALE 0.08838834764831845f  // 1/sqrt(128)

__device__ inline float wave_sum(float v) {
  for (int m = 32; m > 0; m >>= 1) v += __shfl_xor(v, m);
  return v;
}
__device__ inline float wave_max(float v) {
  for (int m = 32; m > 0; m >>= 1) v = fmaxf(v, __shfl_xor(v, m));
  return v;
}

// ---------------- LayerNorm: one block per batch row, 256 threads ----------
__global__ void ln_kernel(const float* __restrict__ x, const float* __restrict__ w,
                          const float* __restrict__ bb, float* __restrict__ o) {
  __shared__ float sred[4];
  int b = blockIdx.x, t = threadIdx.x;
  const float* xr = x + (size_t)b * D_;
  f32x4 v0 = *(const f32x4*)(xr + t * 8);
  f32x4 v1 = *(const f32x4*)(xr + t * 8 + 4);
  float s = (v0[0] + v0[1] + v0[2] + v0[3]) + (v1[0] + v1[1] + v1[2] + v1[3]);
  s = wave_sum(s);
  if ((t & 63) == 0) sred[t >> 6] = s;
  __syncthreads();
  float mu = (sred[0] + sred[1] + sred[2] + sred[3]) * (1.0f / D_);
  __syncthreads();
  float sq = 0.f;
  for (int i = 0; i < 4; i++) {
    float d0 = v0[i] - mu; sq += d0 * d0;
    float d1 = v1[i] - mu; sq += d1 * d1;
  }
  sq = wave_sum(sq);
  if ((t & 63) == 0) sred[t >> 6] = sq;
  __syncthreads();
  float var = (sred[0] + sred[1] + sred[2] + sred[3]) * (1.0f / D_);
  float rs = rsqrtf(var + 1e-5f);
  f32x4 w0 = *(const f32x4*)(w + t * 8), w1 = *(const f32x4*)(w + t * 8 + 4);
  f32x4 c0 = *(const f32x4*)(bb + t * 8), c1 = *(const f32x4*)(bb + t * 8 + 4);
  f32x4 o0, o1;
  for (int i = 0; i < 4; i++) {
    o0[i] = (v0[i] - mu) * rs * w0[i] + c0[i];
    o1[i] = (v1[i] - mu) * rs * w1[i] + c1[i];
  }
  *(f32x4*)(o + (size_t)b * D_ + t * 8) = o0;
  *(f32x4*)(o + (size_t)b * D_ + t * 8 + 4) = o1;
}

// ---------------- Skinny GEMM: C[16,R] = X[16,K] @ W[R,K]^T ----------------
// One wave per 16-row block j0..j0+15, split-K via blockIdx.y.
// MFMA 16x16x16 f16: A lane l holds X[l&15][(l>>4)*4+i]; B lane l holds
// W[j0+(l&15)][(l>>4)*4+i]; D lane l reg r = C[(l>>4)*4+r][j0+(l&15)].
__global__ void gemv_k(const float* __restrict__ W, const float* __restrict__ X,
                       float* __restrict__ part, int R, int K, int kc) {
  int wave = threadIdx.x >> 6, lane = threadIdx.x & 63;
  int j0 = (blockIdx.x * 4 + wave) * 16;
  int k0 = blockIdx.y * kc;
  int col = lane & 15;
  int kg  = (lane >> 4) << 2;
  const float* wp = W + (size_t)(j0 + col) * K + k0 + kg;
  const float* xp = X + (size_t)col * K + k0 + kg;
  f32x4 acc = {0.f, 0.f, 0.f, 0.f};
  #pragma unroll 4
  for (int kk = 0; kk < kc; kk += 16) {
    f32x4 av = *(const f32x4*)xp; xp += 16;
    f32x4 bv = *(const f32x4*)wp; wp += 16;
    f16x4 ah, bh;
    for (int i = 0; i < 4; i++) { ah[i] = (_Float16)av[i]; bh[i] = (_Float16)bv[i]; }
    acc = __builtin_amdgcn_mfma_f32_16x16x16f16(ah, bh, acc, 0, 0, 0);
  }
  // partial[split][j][b], b = kg..kg+3 contiguous
  *(f32x4*)(part + ((size_t)blockIdx.y * R + j0 + col) * 16 + kg) = acc;
}

// ---------------- split-K reduce + epilogues -------------------------------
__global__ void reduce_plain(const float* __restrict__ part, float* __restrict__ out,
                             int R, int S) {
  int i = blockIdx.x * 256 + threadIdx.x;
  int j = i >> 4, b = i & 15;
  float s = 0.f;
  for (int k = 0; k < S; k++) s += part[(size_t)k * R * 16 + i];
  out[(size_t)b * R + j] = s;
}
__global__ void reduce_resid(const float* __restrict__ part, const float* __restrict__ resid,
                             float* __restrict__ out, int R, int S) {
  int i = blockIdx.x * 256 + threadIdx.x;
  int j = i >> 4, b = i & 15;
  float s = 0.f;
  for (int k = 0; k < S; k++) s += part[(size_t)k * R * 16 + i];
  out[(size_t)b * R + j] = resid[(size_t)b * R + j] + s;
}
__global__ void reduce_bias_gelu(const float* __restrict__ part, const float* __restrict__ bias,
                                 float* __restrict__ out, int R, int S) {
  int i = blockIdx.x * 256 + threadIdx.x;
  int j = i >> 4, b = i & 15;
  float s = 0.f;
  for (int k = 0; k < S; k++) s += part[(size_t)k * R * 16 + i];
  float u = s + bias[j];
  out[(size_t)b * R + j] = 0.5f * u * (1.0f + erff(u * 0.70710678118654752f));
}
__global__ void reduce_bias_resid(const float* __restrict__ part, const float* __restrict__ bias,
                                  const float* __restrict__ resid, float* __restrict__ out,
                                  int R, int S) {
  int i = blockIdx.x * 256 + threadIdx.x;
  int j = i >> 4, b = i & 15;
  float s = 0.f;
  for (int k = 0; k < S; k++) s += part[(size_t)k * R * 16 + i];
  out[(size_t)b * R + j] = resid[(size_t)b * R + j] + s + bias[j];
}

// ---------------- flash-decode attention partials --------------------------
// grid (B*H, 16 splits), 256 threads. Each block: 128 past keys.
__global__ void attn_part(const float* __restrict__ qkv, const float* __restrict__ pk,
                          const float* __restrict__ pv, float* __restrict__ pml,
                          float* __restrict__ pacc) {
  int bh = blockIdx.x, split = blockIdx.y;
  int b = bh >> 4, hh = bh & 15;
  int t = threadIdx.x;
  __shared__ f32x4 q_s4[32];
  __shared__ float s_s[128];
  __shared__ float sred[4];
  __shared__ f32x4 redv[8][32];
  if (t < 128) ((float*)q_s4)[t] = qkv[(size_t)b * QKV_R + hh * HD_ + t] * SCALE;
  __syncthreads();
  int l0 = split * 128;
  int lane32 = t & 31, g = t >> 5;
  const float* kbase = pk + (((size_t)b * LP_ + l0) * H_ + hh) * HD_ + lane32 * 4;
  f32x4 qv = q_s4[lane32];
  for (int it = 0; it < 16; it++) {
    int kk = g * 16 + it;
    f32x4 kv = *(const f32x4*)(kbase + (size_t)kk * (H_ * HD_));
    float d = kv[0] * qv[0] + kv[1] * qv[1] + kv[2] * qv[2] + kv[3] * qv[3];
    for (int m = 16; m > 0; m >>= 1) d += __shfl_xor(d, m);
    if (lane32 == 0) s_s[kk] = d;
  }
  __syncthreads();
  float v = (t < 128) ? s_s[t] : -1e30f;
  float mw = wave_max(v);
  if ((t & 63) == 0) sred[t >> 6] = mw;
  __syncthreads();
  float M = fmaxf(fmaxf(sred[0], sred[1]), fmaxf(sred[2], sred[3]));
  __syncthreads();
  float p = (t < 128) ? __expf(v - M) : 0.f;
  float sw = wave_sum(p);
  if ((t & 63) == 0) sred[t >> 6] = sw;
  __syncthreads();
  float L = sred[0] + sred[1] + sred[2] + sred[3];
  if (t < 128) s_s[t] = p;
  if (t == 0) {
    pml[(bh * 16 + split) * 2]     = M;
    pml[(bh * 16 + split) * 2 + 1] = L;
  }
  __syncthreads();
  const float* vbase = pv + (((size_t)b * LP_ + l0) * H_ + hh) * HD_ + lane32 * 4;
  f32x4 acc = {0.f, 0.f, 0.f, 0.f};
  for (int it = 0; it < 16; it++) {
    int kk = g * 16 + it;
    f32x4 vv = *(const f32x4*)(vbase + (size_t)kk * (H_ * HD_));
    float pp = s_s[kk];
    for (int i = 0; i < 4; i++) acc[i] += pp * vv[i];
  }
  redv[g][lane32] = acc;
  __syncthreads();
  if (t < 32) {
    f32x4 o = redv[0][t];
    for (int g2 = 1; g2 < 8; g2++) {
      f32x4 r = redv[g2][t];
      for (int i = 0; i < 4; i++) o[i] += r[i];
    }
    *(f32x4*)(pacc + (size_t)(bh * 16 + split) * HD_ + t * 4) = o;
  }
}

// ---------------- combine splits + fold in new token's K/V -----------------
__global__ void attn_comb(const float* __restrict__ qkv, const float* __restrict__ pml,
                          const float* __restrict__ pacc, float* __restrict__ attn_out) {
  int bh = blockIdx.x, b = bh >> 4, hh = bh & 15;
  int t = threadIdx.x;  // 128
  __shared__ float sred[2];
  float qv = qkv[(size_t)b * QKV_R + hh * HD_ + t];
  float kn = qkv[(size_t)b * QKV_R + D_ + hh * HD_ + t];
  float d = qv * kn;
  d = wave_sum(d);
  if ((t & 63) == 0) sred[t >> 6] = d;
  __syncthreads();
  float s_new = (sred[0] + sred[1]) * SCALE;
  float vn = qkv[(size_t)b * QKV_R + 2 * D_ + hh * HD_ + t];
  float M = s_new;
  for (int s = 0; s < 16; s++) M = fmaxf(M, pml[(bh * 16 + s) * 2]);
  float en = __expf(s_new - M);
  float L = en;
  float o = en * vn;
  for (int s = 0; s < 16; s++) {
    float ms = pml[(bh * 16 + s) * 2], ls = pml[(bh * 16 + s) * 2 + 1];
    float e = __expf(ms - M);
    L += ls * e;
    o += pacc[(size_t)(bh * 16 + s) * HD_ + t] * e;
  }
  attn_out[(size_t)b * D_ + hh * HD_ + t] = o / L;
}

extern "C" void kernel_launch(void* const* d_in, const int* in_sizes, int n_in,
                              void* d_out, int out_size, void* d_ws, size_t ws_size,
                              hipStream_t stream) {
  const float* input  = (const float*)d_in[0];
  const float* pk     = (const float*)d_in[1];
  const float* pv     = (const float*)d_in[2];
  const float* ln0_w  = (const float*)d_in[3];
  const float* ln0_b  = (const float*)d_in[4];
  const float* ln1_w  = (const float*)d_in[5];
  const float* ln1_b  = (const float*)d_in[6];
  const float* wqkv   = (const float*)d_in[7];
  const float* wo     = (const float*)d_in[8];
  const float* fc0_w  = (const float*)d_in[9];
  const float* fc0_b  = (const float*)d_in[10];
  const float* fc1_w  = (const float*)d_in[11];
  const float* fc1_b  = (const float*)d_in[12];
  float* out = (float*)d_out;

  char* wsb = (char*)d_ws;
  float* x_ln     = (float*)(wsb + 0);        // 16x2048
  float* qkv      = (float*)(wsb + 131072);   // 16x6144
  float* attn_out = (float*)(wsb + 524288);   // 16x2048
  float* hbuf     = (float*)(wsb + 655360);   // 16x2048
  float* y0       = (float*)(wsb + 786432);   // 16x2048
  float* act      = (float*)(wsb + 917504);   // 16x8192
  float* pml      = (float*)(wsb + 1441792);  // 256*16*2
  float* pacc     = (float*)(wsb + 1474560);  // 256*16*128
  float* part     = (float*)(wsb + 3571712);  // up to 8*6144*16 floats

  // 1. LN0
  ln_kernel<<<16, 256, 0, stream>>>(input, ln0_w, ln0_b, x_ln);
  // 2. QKV projection (R=6144, K=2048, split 8)
  gemv_k<<<dim3(96, 8), 256, 0, stream>>>(wqkv, x_ln, part, QKV_R, D_, 256);
  reduce_plain<<<384, 256, 0, stream>>>(part, qkv, QKV_R, 8);
  // 3. attention over past KV (flash-decode, 16 splits)
  attn_part<<<dim3(256, 16), 256, 0, stream>>>(qkv, pk, pv, pml, pacc);
  attn_comb<<<256, 128, 0, stream>>>(qkv, pml, pacc, attn_out);
  // 4. output projection + residual (R=2048, K=2048, split 16)
  gemv_k<<<dim3(32, 16), 256, 0, stream>>>(wo, attn_out, part, D_, D_, 128);
  reduce_resid<<<128, 256, 0, stream>>>(part, input, hbuf, D_, 16);
  // 5. LN1
  ln_kernel<<<16, 256, 0, stream>>>(hbuf, ln1_w, ln1_b, y0);
  // 6. FC0 + gelu (R=8192, K=2048, split 4)
  gemv_k<<<dim3(128, 4), 256, 0, stream>>>(fc0_w, y0, part, M_, D_, 512);
  reduce_bias_gelu<<<512, 256, 0, stream>>>(part, fc0_b, act, M_, 4);
  // 7. FC1 + bias + residual (R=2048, K=8192, split 16)
  gemv_k<<<dim3(32, 16), 256, 0, stream>>>(fc1_w, act, part, D_, M_, 512);
  reduce_bias_resid<<<128, 256, 0, stream>>>(part, fc1_b, hbuf, out, D_, 16);
}

// Round 2
// 197.444 us; speedup vs baseline: 1.0372x; 1.0372x over previous
//
#include <hip/hip_runtime.h>
#include <math.h>

typedef __attribute__((ext_vector_type(4))) float f32x4;
typedef __attribute__((ext_vector_type(4))) _Float16 f16x4;

#define B_  16
#define D_  2048
#define H_  16
#define HD_ 128
#define LP_ 2048
#define M_  8192
#define QKV_R (3 * D_)
#define SCALE 0.08838834764831845f  // 1/sqrt(128)
#define NSPLIT 32
#define KPS 64   // keys per split (LP_ / NSPLIT)

__device__ inline float wave_sum(float v) {
  for (int m = 32; m > 0; m >>= 1) v += __shfl_xor(v, m);
  return v;
}

// ---------------- LayerNorm: one block per batch row, 256 threads ----------
__global__ void ln_kernel(const float* __restrict__ x, const float* __restrict__ w,
                          const float* __restrict__ bb, float* __restrict__ o) {
  __shared__ float sred[4];
  int b = blockIdx.x, t = threadIdx.x;
  const float* xr = x + (size_t)b * D_;
  f32x4 v0 = *(const f32x4*)(xr + t * 8);
  f32x4 v1 = *(const f32x4*)(xr + t * 8 + 4);
  float s = (v0[0] + v0[1] + v0[2] + v0[3]) + (v1[0] + v1[1] + v1[2] + v1[3]);
  s = wave_sum(s);
  if ((t & 63) == 0) sred[t >> 6] = s;
  __syncthreads();
  float mu = (sred[0] + sred[1] + sred[2] + sred[3]) * (1.0f / D_);
  __syncthreads();
  float sq = 0.f;
  for (int i = 0; i < 4; i++) {
    float d0 = v0[i] - mu; sq += d0 * d0;
    float d1 = v1[i] - mu; sq += d1 * d1;
  }
  sq = wave_sum(sq);
  if ((t & 63) == 0) sred[t >> 6] = sq;
  __syncthreads();
  float var = (sred[0] + sred[1] + sred[2] + sred[3]) * (1.0f / D_);
  float rs = rsqrtf(var + 1e-5f);
  f32x4 w0 = *(const f32x4*)(w + t * 8), w1 = *(const f32x4*)(w + t * 8 + 4);
  f32x4 c0 = *(const f32x4*)(bb + t * 8), c1 = *(const f32x4*)(bb + t * 8 + 4);
  f32x4 o0, o1;
  for (int i = 0; i < 4; i++) {
    o0[i] = (v0[i] - mu) * rs * w0[i] + c0[i];
    o1[i] = (v1[i] - mu) * rs * w1[i] + c1[i];
  }
  *(f32x4*)(o + (size_t)b * D_ + t * 8) = o0;
  *(f32x4*)(o + (size_t)b * D_ + t * 8 + 4) = o1;
}

// ---------------- Skinny GEMM: C[16,R] = X[16,K] @ W[R,K]^T ----------------
__global__ void gemv_k(const float* __restrict__ W, const float* __restrict__ X,
                       float* __restrict__ part, int R, int K, int kc) {
  int wave = threadIdx.x >> 6, lane = threadIdx.x & 63;
  int j0 = (blockIdx.x * 4 + wave) * 16;
  int k0 = blockIdx.y * kc;
  int col = lane & 15;
  int kg  = (lane >> 4) << 2;
  const float* wp = W + (size_t)(j0 + col) * K + k0 + kg;
  const float* xp = X + (size_t)col * K + k0 + kg;
  f32x4 acc = {0.f, 0.f, 0.f, 0.f};
  #pragma unroll 4
  for (int kk = 0; kk < kc; kk += 16) {
    f32x4 av = *(const f32x4*)xp; xp += 16;
    f32x4 bv = *(const f32x4*)wp; wp += 16;
    f16x4 ah, bh;
    for (int i = 0; i < 4; i++) { ah[i] = (_Float16)av[i]; bh[i] = (_Float16)bv[i]; }
    acc = __builtin_amdgcn_mfma_f32_16x16x16f16(ah, bh, acc, 0, 0, 0);
  }
  *(f32x4*)(part + ((size_t)blockIdx.y * R + j0 + col) * 16 + kg) = acc;
}

// ---------------- split-K reduce + epilogues -------------------------------
__global__ void reduce_plain(const float* __restrict__ part, float* __restrict__ out,
                             int R, int S) {
  int i = blockIdx.x * 256 + threadIdx.x;
  int j = i >> 4, b = i & 15;
  float s = 0.f;
  for (int k = 0; k < S; k++) s += part[(size_t)k * R * 16 + i];
  out[(size_t)b * R + j] = s;
}
__global__ void reduce_resid(const float* __restrict__ part, const float* __restrict__ resid,
                             float* __restrict__ out, int R, int S) {
  int i = blockIdx.x * 256 + threadIdx.x;
  int j = i >> 4, b = i & 15;
  float s = 0.f;
  for (int k = 0; k < S; k++) s += part[(size_t)k * R * 16 + i];
  out[(size_t)b * R + j] = resid[(size_t)b * R + j] + s;
}
__global__ void reduce_bias_gelu(const float* __restrict__ part, const float* __restrict__ bias,
                                 float* __restrict__ out, int R, int S) {
  int i = blockIdx.x * 256 + threadIdx.x;
  int j = i >> 4, b = i & 15;
  float s = 0.f;
  for (int k = 0; k < S; k++) s += part[(size_t)k * R * 16 + i];
  float u = s + bias[j];
  out[(size_t)b * R + j] = 0.5f * u * (1.0f + erff(u * 0.70710678118654752f));
}
__global__ void reduce_bias_resid(const float* __restrict__ part, const float* __restrict__ bias,
                                  const float* __restrict__ resid, float* __restrict__ out,
                                  int R, int S) {
  int i = blockIdx.x * 256 + threadIdx.x;
  int j = i >> 4, b = i & 15;
  float s = 0.f;
  for (int k = 0; k < S; k++) s += part[(size_t)k * R * 16 + i];
  out[(size_t)b * R + j] = resid[(size_t)b * R + j] + s + bias[j];
}

// ---------------- flash-decode attention partials --------------------------
// grid (B, NSPLIT), 256 threads. Block handles ALL 16 heads over KPS keys.
// K/V rows [b, l, :, :] are contiguous (H*HD = 2048 floats = 8 KB): 256
// threads x 32 B cover one key row fully coalesced. Thread t owns head
// h = t>>4, dims d0 = (t&15)*8 .. +8.
__global__ void attn_part(const float* __restrict__ qkv, const float* __restrict__ pk,
                          const float* __restrict__ pv, float* __restrict__ pml,
                          float* __restrict__ pacc) {
  int b = blockIdx.x, split = blockIdx.y;
  int t = threadIdx.x;
  int h = t >> 4, d0 = (t & 15) * 8;
  __shared__ float s_s[16][KPS + 1];   // padded: +1 breaks bank aliasing

  // q fragment (pre-scaled) in registers
  f32x4 q0 = *(const f32x4*)(qkv + (size_t)b * QKV_R + h * HD_ + d0);
  f32x4 q1 = *(const f32x4*)(qkv + (size_t)b * QKV_R + h * HD_ + d0 + 4);
  for (int i = 0; i < 4; i++) { q0[i] *= SCALE; q1[i] *= SCALE; }

  const float* kb = pk + ((size_t)b * LP_ + split * KPS) * D_ + t * 8;
  #pragma unroll 4
  for (int l = 0; l < KPS; l++) {
    f32x4 k0 = *(const f32x4*)(kb + (size_t)l * D_);
    f32x4 k1 = *(const f32x4*)(kb + (size_t)l * D_ + 4);
    float d = q0[0]*k0[0] + q0[1]*k0[1] + q0[2]*k0[2] + q0[3]*k0[3]
            + q1[0]*k1[0] + q1[1]*k1[1] + q1[2]*k1[2] + q1[3]*k1[3];
    d += __shfl_xor(d, 1); d += __shfl_xor(d, 2);
    d += __shfl_xor(d, 4); d += __shfl_xor(d, 8);
    if ((t & 15) == 0) s_s[h][l] = d;
  }
  __syncthreads();

  // partial softmax per head: thread t handles 4 keys of head h
  int l0 = (t & 15) * 4;
  float sv0 = s_s[h][l0], sv1 = s_s[h][l0 + 1], sv2 = s_s[h][l0 + 2], sv3 = s_s[h][l0 + 3];
  float m = fmaxf(fmaxf(sv0, sv1), fmaxf(sv2, sv3));
  m = fmaxf(m, __shfl_xor(m, 1)); m = fmaxf(m, __shfl_xor(m, 2));
  m = fmaxf(m, __shfl_xor(m, 4)); m = fmaxf(m, __shfl_xor(m, 8));
  sv0 = __expf(sv0 - m); sv1 = __expf(sv1 - m);
  sv2 = __expf(sv2 - m); sv3 = __expf(sv3 - m);
  float L = sv0 + sv1 + sv2 + sv3;
  L += __shfl_xor(L, 1); L += __shfl_xor(L, 2);
  L += __shfl_xor(L, 4); L += __shfl_xor(L, 8);
  s_s[h][l0] = sv0; s_s[h][l0 + 1] = sv1; s_s[h][l0 + 2] = sv2; s_s[h][l0 + 3] = sv3;
  if ((t & 15) == 0) {
    pml[((b * NSPLIT + split) * H_ + h) * 2]     = m;
    pml[((b * NSPLIT + split) * H_ + h) * 2 + 1] = L;
  }
  __syncthreads();

  // V pass: same coalesced stream, broadcast p from LDS
  const float* vb = pv + ((size_t)b * LP_ + split * KPS) * D_ + t * 8;
  f32x4 a0 = {0.f, 0.f, 0.f, 0.f}, a1 = {0.f, 0.f, 0.f, 0.f};
  #pragma unroll 4
  for (int l = 0; l < KPS; l++) {
    f32x4 v0 = *(const f32x4*)(vb + (size_t)l * D_);
    f32x4 v1 = *(const f32x4*)(vb + (size_t)l * D_ + 4);
    float p = s_s[h][l];
    for (int i = 0; i < 4; i++) { a0[i] += p * v0[i]; a1[i] += p * v1[i]; }
  }
  size_t oi = (((size_t)b * NSPLIT + split) * H_ + h) * HD_ + d0;
  *(f32x4*)(pacc + oi) = a0;
  *(f32x4*)(pacc + oi + 4) = a1;
}

// ---------------- combine splits + fold in new token's K/V -----------------
__global__ void attn_comb(const float* __restrict__ qkv, const float* __restrict__ pml,
                          const float* __restrict__ pacc, float* __restrict__ attn_out) {
  int bh = blockIdx.x, b = bh >> 4, hh = bh & 15;
  int t = threadIdx.x;  // 128
  __shared__ float sred[2];
  float qv = qkv[(size_t)b * QKV_R + hh * HD_ + t];
  float kn = qkv[(size_t)b * QKV_R + D_ + hh * HD_ + t];
  float d = qv * kn;
  d = wave_sum(d);
  if ((t & 63) == 0) sred[t >> 6] = d;
  __syncthreads();
  float s_new = (sred[0] + sred[1]) * SCALE;
  float vn = qkv[(size_t)b * QKV_R + 2 * D_ + hh * HD_ + t];
  float M = s_new;
  for (int s = 0; s < NSPLIT; s++)
    M = fmaxf(M, pml[((b * NSPLIT + s) * H_ + hh) * 2]);
  float en = __expf(s_new - M);
  float L = en;
  float o = en * vn;
  for (int s = 0; s < NSPLIT; s++) {
    float ms = pml[((b * NSPLIT + s) * H_ + hh) * 2];
    float ls = pml[((b * NSPLIT + s) * H_ + hh) * 2 + 1];
    float e = __expf(ms - M);
    L += ls * e;
    o += pacc[(((size_t)b * NSPLIT + s) * H_ + hh) * HD_ + t] * e;
  }
  attn_out[(size_t)b * D_ + hh * HD_ + t] = o / L;
}

extern "C" void kernel_launch(void* const* d_in, const int* in_sizes, int n_in,
                              void* d_out, int out_size, void* d_ws, size_t ws_size,
                              hipStream_t stream) {
  const float* input  = (const float*)d_in[0];
  const float* pk     = (const float*)d_in[1];
  const float* pv     = (const float*)d_in[2];
  const float* ln0_w  = (const float*)d_in[3];
  const float* ln0_b  = (const float*)d_in[4];
  const float* ln1_w  = (const float*)d_in[5];
  const float* ln1_b  = (const float*)d_in[6];
  const float* wqkv   = (const float*)d_in[7];
  const float* wo     = (const float*)d_in[8];
  const float* fc0_w  = (const float*)d_in[9];
  const float* fc0_b  = (const float*)d_in[10];
  const float* fc1_w  = (const float*)d_in[11];
  const float* fc1_b  = (const float*)d_in[12];
  float* out = (float*)d_out;

  char* wsb = (char*)d_ws;
  float* x_ln     = (float*)(wsb + 0);        // 16x2048            128 KB
  float* qkv      = (float*)(wsb + 131072);   // 16x6144            384 KB
  float* attn_out = (float*)(wsb + 524288);   // 16x2048            128 KB
  float* hbuf     = (float*)(wsb + 655360);   // 16x2048            128 KB
  float* y0       = (float*)(wsb + 786432);   // 16x2048            128 KB
  float* act      = (float*)(wsb + 917504);   // 16x8192            512 KB
  float* pml      = (float*)(wsb + 1441792);  // 16*32*16*2          64 KB
  float* pacc     = (float*)(wsb + 1507328);  // 16*32*16*128         4 MB
  float* part     = (float*)(wsb + 5701632);  // up to 8*6144*16      3 MB

  // 1. LN0
  ln_kernel<<<16, 256, 0, stream>>>(input, ln0_w, ln0_b, x_ln);
  // 2. QKV projection (R=6144, K=2048, split 8)
  gemv_k<<<dim3(96, 8), 256, 0, stream>>>(wqkv, x_ln, part, QKV_R, D_, 256);
  reduce_plain<<<384, 256, 0, stream>>>(part, qkv, QKV_R, 8);
  // 3. attention over past KV (flash-decode, all heads per block, 32 splits)
  attn_part<<<dim3(B_, NSPLIT), 256, 0, stream>>>(qkv, pk, pv, pml, pacc);
  attn_comb<<<256, 128, 0, stream>>>(qkv, pml, pacc, attn_out);
  // 4. output projection + residual (R=2048, K=2048, split 16)
  gemv_k<<<dim3(32, 16), 256, 0, stream>>>(wo, attn_out, part, D_, D_, 128);
  reduce_resid<<<128, 256, 0, stream>>>(part, input, hbuf, D_, 16);
  // 5. LN1
  ln_kernel<<<16, 256, 0, stream>>>(hbuf, ln1_w, ln1_b, y0);
  // 6. FC0 + gelu (R=8192, K=2048, split 4)
  gemv_k<<<dim3(128, 4), 256, 0, stream>>>(fc0_w, y0, part, M_, D_, 512);
  reduce_bias_gelu<<<512, 256, 0, stream>>>(part, fc0_b, act, M_, 4);
  // 7. FC1 + bias + residual (R=2048, K=8192, split 16)
  gemv_k<<<dim3(32, 16), 256, 0, stream>>>(fc1_w, act, part, D_, M_, 512);
  reduce_bias_resid<<<128, 256, 0, stream>>>(part, fc1_b, hbuf, out, D_, 16);
}